// Round 7
// baseline (93.974 us; speedup 1.0000x reference)
//
#include <hip/hip_runtime.h>
#include <cstdint>

typedef unsigned short ushort_t;
typedef __attribute__((ext_vector_type(4))) float f32x4;
typedef __attribute__((ext_vector_type(8))) __bf16 bf16x8;
typedef __attribute__((ext_vector_type(8))) unsigned short ushort8;

#define NB 16384
#define DK 1024   // IN + H

#define MFMA16(a, b, c) __builtin_amdgcn_mfma_f32_16x16x32_bf16(a, b, c, 0, 0, 0)

// f32 -> bf16 bits, round-to-nearest-even
__device__ __forceinline__ unsigned short f2b(float f) {
    unsigned u = __builtin_bit_cast(unsigned, f);
    unsigned r = u + 0x7fffu + ((u >> 16) & 1u);
    return (unsigned short)(r >> 16);
}
__device__ __forceinline__ float b2f(ushort_t b) {
    unsigned u = ((unsigned)b) << 16;
    return __builtin_bit_cast(float, u);
}
__device__ __forceinline__ float fast_sigmoid(float x) {
    return __fdividef(1.0f, 1.0f + __expf(-x));
}
__device__ __forceinline__ float fast_tanh(float x) {
    return __fdividef(2.0f, 1.0f + __expf(-2.0f * x)) - 1.0f;
}

// async global->LDS, 16B per lane (LDS dest = wave-uniform base + lane*16)
__device__ __forceinline__ void gll16(const void* g, void* lds) {
    __builtin_amdgcn_global_load_lds(
        (__attribute__((address_space(1))) unsigned int*)(uintptr_t)g,
        (__attribute__((address_space(3))) unsigned int*)(unsigned int)(uintptr_t)lds,
        16, 0, 0);
}

// ---------------- prep kernels (linear layouts) ----------------

// blocks 0..4095: x -> XB ; 4096..8191: h -> HB
__global__ __launch_bounds__(256) void k_cvt(const float* __restrict__ x,
                                             const float* __restrict__ h,
                                             ushort_t* __restrict__ XB,
                                             ushort_t* __restrict__ HB) {
    int b = blockIdx.x;
    const float* s;
    ushort_t* d;
    if (b < 4096) { s = x; d = XB; } else { s = h; d = HB; b -= 4096; }
    size_t g = (size_t)b * 256 + threadIdx.x;
    const float* p = s + g * 8;
    f32x4 f0 = *(const f32x4*)p;
    f32x4 f1 = *(const f32x4*)(p + 4);
    ushort8 o;
#pragma unroll
    for (int j = 0; j < 4; ++j) { o[j] = f2b(f0[j]); o[j + 4] = f2b(f1[j]); }
    *(ushort8*)(d + g * 8) = o;
}

// z=0: W_in [1024][1024] -> WTI [1024][1024] ; z=1: W_out [1024][512] -> WTO [512][1024]
__global__ __launch_bounds__(256) void k_transpose_w(const float* __restrict__ Wi,
                                                     const float* __restrict__ Wo,
                                                     ushort_t* __restrict__ WTI,
                                                     ushort_t* __restrict__ WTO) {
    const int z = blockIdx.z;
    if (z == 1 && blockIdx.x >= 16) return;
    const float* W = (z == 0) ? Wi : Wo;
    ushort_t* Wt = (z == 0) ? WTI : WTO;
    const int ncols = (z == 0) ? 1024 : 512;
    __shared__ float tile[32][33];
    int n0 = blockIdx.x * 32, k0 = blockIdx.y * 32;
    int tx = threadIdx.x & 31, ty = threadIdx.x >> 5;  // 32x8
#pragma unroll
    for (int i = 0; i < 32; i += 8)
        tile[ty + i][tx] = W[(size_t)(k0 + ty + i) * ncols + n0 + tx];
    __syncthreads();
#pragma unroll
    for (int i = 0; i < 32; i += 8)
        Wt[(size_t)(n0 + ty + i) * DK + k0 + tx] = f2b(tile[tx][ty + i]);
}

// ---------------- GEMM 1: lin = [x,h] @ W_in, fused gate epilogue ----------------
// Structure-parity with the proven ~900TF shape: per iter/wave 16 MFMA, 8 ds_read,
// block: 4 gll16; acc = 64 regs. Block = 128 rows x 64 PAIRED cols
// (learn col c and forget col c+512 computed in the same thread).
__global__ __launch_bounds__(256, 2) void k_gemm1(
    const ushort_t* __restrict__ XB, const ushort_t* __restrict__ HB,
    const ushort_t* __restrict__ WT, const float* __restrict__ b_in,
    float* __restrict__ hnew, ushort_t* __restrict__ HN) {
    __shared__ ushort_t As[2][128 * 32];      // 8KB each
    __shared__ ushort_t Bs[2][2][64 * 32];    // [dbuf][L/F] 4KB each ; total 32KB

    const int t = threadIdx.x;
    const int lane = t & 63;
    const int wave = t >> 6;
    const int wm = wave >> 1, wn = wave & 1;  // 2x2 waves; wave tile 64 rows x 32 pairs
    const int m0 = blockIdx.x * 128;
    const int n0 = blockIdx.y * 64;           // paired col base, in [0,512)

    f32x4 accL[4][2] = {};
    f32x4 accF[4][2] = {};

    const int srow = t >> 2;        // 0..63
    const int skel = (t & 3) * 8;
    const size_t arow = (size_t)(m0 + srow) * 512;
    const ushort_t* gBL = WT + (size_t)(n0 + srow) * DK + skel;
    const ushort_t* gBF = WT + (size_t)(n0 + 512 + srow) * DK + skel;

    auto stage = [&](int it, int buf) {   // 4 gll16
        const int kt = it * 32;
        const ushort_t* abase =
            (kt < 512) ? (XB + arow + kt + skel) : (HB + arow + (kt - 512) + skel);
        ushort_t* a = &As[buf][t * 8];
        gll16(abase, a);
        gll16(abase + 64 * 512, a + 64 * 32);
        gll16(gBL + kt, &Bs[buf][0][t * 8]);
        gll16(gBF + kt, &Bs[buf][1][t * 8]);
    };

    const int fr = lane & 15;
    const int kq = (lane >> 4) * 8;

    stage(0, 0);
    int cur = 0;
    for (int it = 0; it < 32; ++it) {
        asm volatile("s_waitcnt vmcnt(0)" ::: "memory");
        __syncthreads();
        if (it + 1 < 32) stage(it + 1, cur ^ 1);

        bf16x8 av[4], blv[2], bfv[2];
#pragma unroll
        for (int i = 0; i < 4; ++i)
            av[i] = *(const bf16x8*)(&As[cur][(wm * 64 + i * 16 + fr) * 32 + kq]);
#pragma unroll
        for (int j = 0; j < 2; ++j) {
            blv[j] = *(const bf16x8*)(&Bs[cur][0][(wn * 32 + j * 16 + fr) * 32 + kq]);
            bfv[j] = *(const bf16x8*)(&Bs[cur][1][(wn * 32 + j * 16 + fr) * 32 + kq]);
        }
#pragma unroll
        for (int i = 0; i < 4; ++i)
#pragma unroll
            for (int j = 0; j < 2; ++j) {
                accL[i][j] = MFMA16(av[i], blv[j], accL[i][j]);
                accF[i][j] = MFMA16(av[i], bfv[j], accF[i][j]);
            }
        cur ^= 1;
    }

    // epilogue: C/D map col=lane&15, row=(lane>>4)*4+reg
    const int fq = lane >> 4;
#pragma unroll
    for (int i = 0; i < 4; ++i)
#pragma unroll
        for (int j = 0; j < 2; ++j) {
            const int c = n0 + wn * 32 + j * 16 + fr;
            const float bl = b_in[c];
            const float bf = b_in[c + 512];
#pragma unroll
            for (int rr = 0; rr < 4; ++rr) {
                const int row = m0 + wm * 64 + i * 16 + fq * 4 + rr;
                float lp = accL[i][j][rr] + bl;
                float fp = accF[i][j][rr] + bf;
                float hv = b2f(HB[(size_t)row * 512 + c]);
                float fm = fast_sigmoid(fp);
                float lr = fast_tanh(lp);
                float hn = fm * hv + (1.0f - fm) * lr;
                hnew[(size_t)row * 512 + c] = hn;
                HN[(size_t)row * 512 + c] = f2b(hn);
            }
        }
}

// ---------------- GEMM 2: out = tanh([x,h_new] @ W_out + b_out) ----------------
// Proven R3/R4 128^2 2-phase dbuf form (~900 TF).
__global__ __launch_bounds__(256, 2) void k_gemm2(
    const ushort_t* __restrict__ XB, const ushort_t* __restrict__ HN,
    const ushort_t* __restrict__ WT, const float* __restrict__ b_out,
    float* __restrict__ out) {
    __shared__ ushort_t As[2][128 * 32];
    __shared__ ushort_t Bs[2][128 * 32];

    const int t = threadIdx.x;
    const int lane = t & 63;
    const int wave = t >> 6;
    const int wm = wave >> 1, wn = wave & 1;
    const int m0 = blockIdx.x * 128;
    const int n0 = blockIdx.y * 128;

    f32x4 acc[4][4] = {};

    const int srow = t >> 2;
    const int skel = (t & 3) * 8;
    const size_t arow = (size_t)(m0 + srow) * 512;
    const ushort_t* gB = WT + (size_t)(n0 + srow) * DK + skel;

    auto stage = [&](int it, int buf) {
        const int kt = it * 32;
        const ushort_t* abase =
            (kt < 512) ? (XB + arow + kt + skel) : (HN + arow + (kt - 512) + skel);
        ushort_t* a = &As[buf][t * 8];
        ushort_t* b = &Bs[buf][t * 8];
        gll16(abase, a);
        gll16(abase + 64 * 512, a + 64 * 32);
        gll16(gB + kt, b);
        gll16(gB + kt + 64 * DK, b + 64 * 32);
    };

    const int fr = lane & 15;
    const int kq = (lane >> 4) * 8;

    stage(0, 0);
    int cur = 0;
    for (int it = 0; it < 32; ++it) {
        asm volatile("s_waitcnt vmcnt(0)" ::: "memory");
        __syncthreads();
        if (it + 1 < 32) stage(it + 1, cur ^ 1);

        bf16x8 av[4], bv[4];
#pragma unroll
        for (int i = 0; i < 4; ++i) {
            av[i] = *(const bf16x8*)(&As[cur][(wm * 64 + i * 16 + fr) * 32 + kq]);
            bv[i] = *(const bf16x8*)(&Bs[cur][(wn * 64 + i * 16 + fr) * 32 + kq]);
        }
#pragma unroll
        for (int i = 0; i < 4; ++i)
#pragma unroll
            for (int j = 0; j < 4; ++j)
                acc[i][j] = MFMA16(av[i], bv[j], acc[i][j]);
        cur ^= 1;
    }

    const int fq = lane >> 4;
#pragma unroll
    for (int i = 0; i < 4; ++i)
#pragma unroll
        for (int j = 0; j < 4; ++j) {
            const int c = n0 + wn * 64 + j * 16 + fr;
            const float bo = b_out[c];
#pragma unroll
            for (int rr = 0; rr < 4; ++rr) {
                const int row = m0 + wm * 64 + i * 16 + fq * 4 + rr;
                out[(size_t)row * 512 + c] = fast_tanh(acc[i][j][rr] + bo);
            }
        }
}

extern "C" void kernel_launch(void* const* d_in, const int* in_sizes, int n_in,
                              void* d_out, int out_size, void* d_ws, size_t ws_size,
                              hipStream_t stream) {
    const float* x = (const float*)d_in[0];
    const float* h = (const float*)d_in[1];
    const float* W_in = (const float*)d_in[2];
    const float* b_in = (const float*)d_in[3];
    const float* W_out = (const float*)d_in[4];
    const float* b_out = (const float*)d_in[5];

    float* out = (float*)d_out;                    // [16384][512]
    float* hnew = out + (size_t)NB * 512;          // [16384][512]

    ushort_t* XB = (ushort_t*)d_ws;
    ushort_t* HB = XB + (size_t)NB * 512;
    ushort_t* HN = HB + (size_t)NB * 512;
    ushort_t* WTI = HN + (size_t)NB * 512;
    ushort_t* WTO = WTI + (size_t)1024 * 1024;

    k_cvt<<<8192, 256, 0, stream>>>(x, h, XB, HB);
    k_transpose_w<<<dim3(32, 32, 2), 256, 0, stream>>>(W_in, W_out, WTI, WTO);
    k_gemm1<<<dim3(128, 8), 256, 0, stream>>>(XB, HB, WTI, b_in, hnew, HN);
    k_gemm2<<<dim3(128, 4), 256, 0, stream>>>(XB, HN, WTO, b_out, out);
}